// Round 14
// baseline (454.566 us; speedup 1.0000x reference)
//
#include <hip/hip_runtime.h>
#include <cstdint>
#include <cstddef>

// ClusterProtoNetwork:
//  1) prep_sw: W split-transpose || sup->bf16 hi/lo
//  2) gemm_supq: sup GEMM (512 blk) || qry->bf16 convert (256 blk)
//  3) gram_part: K-split x4 gram partials (1024 blk, 4/CU)
//  4) greduce: fixed-order partial sum (skip diag) || f64 diag (1024 blk)
//  5) kmeans3 (1 wave/class) -> proto1 -> proto2p (protos + |p|^2)
//  6) gemm_qry_dist: qry GEMM + 2-pass fused cdist epilogue (41 KB LDS, 3/CU)
//  7) distred: fixed-order slice reduction -> -sqrt
// JAX threefry (partitionable) RNG on-device.

typedef __attribute__((ext_vector_type(4))) float f32x4;
typedef __attribute__((ext_vector_type(8))) short s16x8;
typedef __attribute__((ext_vector_type(4))) short s16x4;
typedef __attribute__((ext_vector_type(8))) __bf16 bf16x8;

__device__ __forceinline__ unsigned short f2bf(float f) {
  unsigned u = __float_as_uint(f);
  return (unsigned short)((u + 0x7FFFu + ((u >> 16) & 1u)) >> 16);  // RTNE
}
__device__ __forceinline__ float bf2f(unsigned short h) {
  return __uint_as_float(((unsigned)h) << 16);
}

typedef const __attribute__((address_space(1))) void GV;
typedef __attribute__((address_space(3))) void LV;
__device__ __forceinline__ void gload_lds16(const void* g, void* l) {
  __builtin_amdgcn_global_load_lds((GV*)g, (LV*)l, 16, 0, 0);
}
__device__ __forceinline__ f32x4 mfma16(bf16x8 a, bf16x8 b, f32x4 c) {
  return __builtin_amdgcn_mfma_f32_16x16x32_bf16(a, b, c, 0, 0, 0);
}
__device__ __forceinline__ float wave_sum(float v) {
#pragma unroll
  for (int st = 1; st < 64; st <<= 1) v += __shfl_xor(v, st);
  return v;
}

// ---------------- Threefry-2x32 (JAX-exact, 20 rounds) ----------------
__device__ __forceinline__ void tf2x32(unsigned k0, unsigned k1, unsigned x0,
                                       unsigned x1, unsigned& y0, unsigned& y1) {
  unsigned ks0 = k0, ks1 = k1, ks2 = k0 ^ k1 ^ 0x1BD11BDAu;
  x0 += ks0; x1 += ks1;
  const int rA[4] = {13, 15, 26, 6};
  const int rB[4] = {17, 29, 16, 24};
#define ROTL(v, d) (((v) << (d)) | ((v) >> (32 - (d))))
#define RG(R)                                     \
  _Pragma("unroll") for (int i = 0; i < 4; i++) { \
    x0 += x1; x1 = ROTL(x1, R[i]); x1 ^= x0;      \
  }
  RG(rA); x0 += ks1; x1 += ks2 + 1u;
  RG(rB); x0 += ks2; x1 += ks0 + 2u;
  RG(rA); x0 += ks0; x1 += ks1 + 3u;
  RG(rB); x0 += ks1; x1 += ks2 + 4u;
  RG(rA); x0 += ks2; x1 += ks0 + 5u;
#undef RG
#undef ROTL
  y0 = x0; y1 = x1;
}

// ---- 1. prep_sw: W -> WhiT/WloT (transposed split) || sup -> Shi/Slo ------
__global__ __launch_bounds__(256) void prep_sw_k(
    const float* __restrict__ W, const float* __restrict__ sup,
    short* __restrict__ WhiT, short* __restrict__ WloT,
    short* __restrict__ Shi, short* __restrict__ Slo) {
  __shared__ float tile[64][65];
  int t = threadIdx.x;
  if (blockIdx.x < 1024) {  // prepw: 64 k-tiles x 16 n-tiles of 64x64
    int bk = blockIdx.x & 63, bn = blockIdx.x >> 6;
#pragma unroll
    for (int i = 0; i < 4; i++) {
      int row = i * 16 + (t >> 4);
      int col = (t & 15) * 4;
      f32x4 v =
          *(const f32x4*)(W + (size_t)(bk * 64 + row) * 1024 + bn * 64 + col);
      tile[row][col + 0] = v[0]; tile[row][col + 1] = v[1];
      tile[row][col + 2] = v[2]; tile[row][col + 3] = v[3];
    }
    __syncthreads();
#pragma unroll
    for (int i = 0; i < 4; i++) {
      int nrow = i * 16 + (t >> 4);
      int kcol = (t & 15) * 4;
      s16x4 hv, lv;
#pragma unroll
      for (int e = 0; e < 4; e++) {
        float v = tile[kcol + e][nrow];
        unsigned short h = f2bf(v);
        hv[e] = (short)h;
        lv[e] = (short)f2bf(v - bf2f(h));
      }
      size_t off = (size_t)(bn * 64 + nrow) * 4096 + bk * 64 + kcol;
      *(s16x4*)(WhiT + off) = hv;
      *(s16x4*)(WloT + off) = lv;
    }
  } else {  // sup convert: grid-stride over 2M 8-elem chunks
    const size_t sup_n8 = (size_t)4096 * 4096 / 8;
    size_t stride = (size_t)(gridDim.x - 1024) * 256;
    for (size_t gid = (size_t)(blockIdx.x - 1024) * 256 + t; gid < sup_n8;
         gid += stride) {
      const float* src = sup + gid * 8;
      f32x4 v0 = *(const f32x4*)src, v1 = *(const f32x4*)(src + 4);
      s16x8 h, l;
#pragma unroll
      for (int e = 0; e < 4; e++) {
        unsigned short hh = f2bf(v0[e]);
        h[e] = (short)hh; l[e] = (short)f2bf(v0[e] - bf2f(hh));
      }
#pragma unroll
      for (int e = 0; e < 4; e++) {
        unsigned short hh = f2bf(v1[e]);
        h[4 + e] = (short)hh; l[4 + e] = (short)f2bf(v1[e] - bf2f(hh));
      }
      *(s16x8*)(Shi + gid * 8) = h;
      *(s16x8*)(Slo + gid * 8) = l;
    }
  }
}

// ---- 2. gemm_supq: sup GEMM (512 blk, BM=64, 3-product) || qry convert ----
__global__ __launch_bounds__(256) void gemm_supq_k(
    const short* __restrict__ Shi, const short* __restrict__ Slo,
    const short* __restrict__ WhiT, const short* __restrict__ WloT,
    const float* __restrict__ bias, float* __restrict__ emb,
    const float* __restrict__ qry, short* __restrict__ Qhi) {
  __shared__ short lds[24576];  // 48 KiB (3 blk/CU)
  const int t = threadIdx.x;
  if (blockIdx.x < 512) {
    short* Ah = lds;              // [64][64]
    short* Al = lds + 4096;       // [64][64]
    short* Bh = lds + 8192;       // [128][64]
    short* Bl = lds + 16384;      // [128][64]
    const int bid = blockIdx.x;
    const int bm = bid & 63, bn = bid >> 6;  // siblings +64 -> same XCD
    const int lane = t & 63, w = t >> 6;
    const int wr = w >> 1, wc = w & 1;  // wave tile 32 x 64
    const int fr = lane & 15, kg = lane >> 4;
    const int ls = lane >> 3, lc = lane & 7;
    const short* Ag = Shi + (size_t)bm * 64 * 4096;
    const short* Alg = Slo + (size_t)bm * 64 * 4096;
    f32x4 acc[2][4] = {};

    for (int kt = 0; kt < 64; ++kt) {
      const int k0 = kt * 64;
      __syncthreads();
      const int cch = (lc ^ ls) * 8;
#pragma unroll
      for (int j = 0; j < 2; j++) {
        int rowl = w * 16 + j * 8 + ls;
        size_t aoff = (size_t)rowl * 4096 + k0 + cch;
        int ldst = (w * 16 + j * 8) * 64;
        gload_lds16(Ag + aoff, Ah + ldst);
        gload_lds16(Alg + aoff, Al + ldst);
      }
#pragma unroll
      for (int j = 0; j < 4; j++) {
        int rowl = w * 32 + j * 8 + ls;
        size_t boff = (size_t)(bn * 128 + rowl) * 4096 + k0 + cch;
        int ldst = (w * 32 + j * 8) * 64;
        gload_lds16(WhiT + boff, Bh + ldst);
        gload_lds16(WloT + boff, Bl + ldst);
      }
      __syncthreads();
#pragma unroll
      for (int ks = 0; ks < 2; ++ks) {
        const int cx = ((ks * 4 + kg) ^ (fr & 7)) * 8;
        bf16x8 ahf[2], alf[2], bhf[4], blf[4];
#pragma unroll
        for (int mi = 0; mi < 2; mi++) {
          int arow = wr * 32 + mi * 16 + fr;
          ahf[mi] =
              __builtin_bit_cast(bf16x8, *(const s16x8*)(Ah + arow * 64 + cx));
          alf[mi] =
              __builtin_bit_cast(bf16x8, *(const s16x8*)(Al + arow * 64 + cx));
        }
#pragma unroll
        for (int ni = 0; ni < 4; ni++) {
          int brow = wc * 64 + ni * 16 + fr;
          bhf[ni] =
              __builtin_bit_cast(bf16x8, *(const s16x8*)(Bh + brow * 64 + cx));
          blf[ni] =
              __builtin_bit_cast(bf16x8, *(const s16x8*)(Bl + brow * 64 + cx));
        }
#pragma unroll
        for (int mi = 0; mi < 2; mi++)
#pragma unroll
          for (int ni = 0; ni < 4; ni++) {
            acc[mi][ni] = mfma16(ahf[mi], bhf[ni], acc[mi][ni]);
            acc[mi][ni] = mfma16(ahf[mi], blf[ni], acc[mi][ni]);
            acc[mi][ni] = mfma16(alf[mi], bhf[ni], acc[mi][ni]);
          }
      }
    }
#pragma unroll
    for (int ni = 0; ni < 4; ni++) {
      int gc = bn * 128 + wc * 64 + ni * 16 + fr;
      float bv = bias[gc];
#pragma unroll
      for (int mi = 0; mi < 2; mi++) {
        int gr = bm * 64 + wr * 32 + mi * 16 + kg * 4;
#pragma unroll
        for (int r = 0; r < 4; r++)
          emb[(size_t)(gr + r) * 1024 + gc] = acc[mi][ni][r] + bv;
      }
    }
  } else {
    // qry convert: grid-stride, hidden under sup GEMM (idle slot + spare BW)
    const size_t qry_n8 = (size_t)8192 * 4096 / 8;
    size_t stride = (size_t)(gridDim.x - 512) * 256;
    for (size_t gid = (size_t)(blockIdx.x - 512) * 256 + t; gid < qry_n8;
         gid += stride) {
      const float* src = qry + gid * 8;
      f32x4 v0 = *(const f32x4*)src, v1 = *(const f32x4*)(src + 4);
      s16x8 h;
#pragma unroll
      for (int e = 0; e < 4; e++) h[e] = (short)f2bf(v0[e]);
#pragma unroll
      for (int e = 0; e < 4; e++) h[4 + e] = (short)f2bf(v1[e]);
      *(s16x8*)(Qhi + gid * 8) = h;
    }
  }
}

// ---- 3. gram_part: K-split x4, K-major conflict-free LDS ------------------
// block = kq*256 + c*16 + tile; writes Gp[kq][c][64x64 tile] (incl diag).
__global__ __launch_bounds__(256) void gram_part_k(
    const float* __restrict__ emb, float* __restrict__ Gp) {
  int b = blockIdx.x;
  int kq = b >> 8, rem = b & 255;
  int c = rem >> 4, tl = rem & 15, ti = tl >> 2, tj = tl & 3;
  __shared__ float AsT[32][68];  // [kk][row]
  __shared__ float BsT[32][68];  // [kk][col]
  int t = threadIdx.x, ty = t >> 4, tx = t & 15;
  const float* base = emb + (size_t)c * 256 * 1024;
  float acc[4][4] = {};
  for (int k0 = kq * 256; k0 < kq * 256 + 256; k0 += 32) {
    __syncthreads();
    {
      int r = t >> 2, seg = t & 3;
      const float* pa = base + (size_t)(ti * 64 + r) * 1024 + k0 + seg * 8;
      f32x4 va0 = *(const f32x4*)pa, va1 = *(const f32x4*)(pa + 4);
#pragma unroll
      for (int e = 0; e < 4; e++) AsT[seg * 8 + e][r] = va0[e];
#pragma unroll
      for (int e = 0; e < 4; e++) AsT[seg * 8 + 4 + e][r] = va1[e];
      const float* pb = base + (size_t)(tj * 64 + r) * 1024 + k0 + seg * 8;
      f32x4 vb0 = *(const f32x4*)pb, vb1 = *(const f32x4*)(pb + 4);
#pragma unroll
      for (int e = 0; e < 4; e++) BsT[seg * 8 + e][r] = vb0[e];
#pragma unroll
      for (int e = 0; e < 4; e++) BsT[seg * 8 + 4 + e][r] = vb1[e];
    }
    __syncthreads();
#pragma unroll 4
    for (int kk = 0; kk < 32; kk++) {
      f32x4 av = *(const f32x4*)(&AsT[kk][ty * 4]);
      f32x4 bv = *(const f32x4*)(&BsT[kk][tx * 4]);
#pragma unroll
      for (int jdx = 0; jdx < 4; jdx++) {
        acc[0][jdx] = fmaf(av[0], bv[jdx], acc[0][jdx]);
        acc[1][jdx] = fmaf(av[1], bv[jdx], acc[1][jdx]);
        acc[2][jdx] = fmaf(av[2], bv[jdx], acc[2][jdx]);
        acc[3][jdx] = fmaf(av[3], bv[jdx], acc[3][jdx]);
      }
    }
  }
  float* dst = Gp + ((size_t)kq * 16 + c) * 65536;
#pragma unroll
  for (int i = 0; i < 4; i++) {
    int gr = ti * 64 + ty * 4 + i;
#pragma unroll
    for (int j = 0; j < 4; j++)
      dst[(size_t)gr * 256 + tj * 64 + tx * 4 + j] = acc[i][j];
  }
}

// ---- 4. greduce: fixed-order partial sum (skip diag) || f64 diag ----------
__global__ __launch_bounds__(256) void greduce_k(const float* __restrict__ Gp,
                                                 const float* __restrict__ emb,
                                                 float* __restrict__ G) {
  if (blockIdx.x < 1024) {
    size_t cell0 = ((size_t)blockIdx.x * 256 + threadIdx.x) * 4;  // 1M cells
    int c = (int)(cell0 >> 16);
    int within = (int)(cell0 & 65535);
    int gr = within >> 8, gc0 = within & 255;
    f32x4 s = {};
#pragma unroll
    for (int kq = 0; kq < 4; kq++) {
      f32x4 v = *(const f32x4*)(Gp + (((size_t)kq * 16 + c) * 65536 +
                                      (size_t)gr * 256 + gc0));
#pragma unroll
      for (int e = 0; e < 4; e++) s[e] += v[e];
    }
#pragma unroll
    for (int e = 0; e < 4; e++)
      if (gr != gc0 + e)  // diagonal owned by diag blocks
        G[(size_t)c * 65536 + (size_t)gr * 256 + gc0 + e] = s[e];
  } else {
    int r = (blockIdx.x - 1024) * 4 + (threadIdx.x >> 6);  // support row
    int lane = threadIdx.x & 63;
    const float* x = emb + (size_t)r * 1024;
    double acc = 0.0;
#pragma unroll
    for (int ch = 0; ch < 16; ch++) {
      float v = x[ch * 64 + lane];
      acc = fma((double)v, (double)v, acc);
    }
#pragma unroll
    for (int st = 1; st < 64; st <<= 1) acc += __shfl_xor(acc, st);
    if (lane == 0) {
      int c = r >> 8, i = r & 255;
      G[(size_t)c * 65536 + (size_t)i * 256 + i] = (float)acc;
    }
  }
}

// ---- 2'. fallback GEMM (in-loop convert; used when ws too small) ----------
__global__ __launch_bounds__(256) void gemm_all_k(
    const float* __restrict__ sup, const float* __restrict__ qry,
    const short* __restrict__ WhiT, const short* __restrict__ WloT,
    const float* __restrict__ bias, float* __restrict__ emb) {
  __shared__ short lds[4 * 128 * 64];
  short* Ah = lds;
  short* Al = lds + 8192;
  short* Bh = lds + 16384;
  short* Bl = lds + 24576;
  const int bid = blockIdx.x;
  const int bm = bid % 96, bn = bid / 96;
  const bool is_sup = bm < 32;
  const int t = threadIdx.x, lane = t & 63, w = t >> 6;
  const int wr = w >> 1, wc = w & 1;
  const int fr = lane & 15, kg = lane >> 4;
  const float* Abase = is_sup ? (sup + (size_t)bm * 128 * 4096)
                              : (qry + (size_t)(bm - 32) * 128 * 4096);
  f32x4 acc[4][4] = {};
  const int ls = lane >> 3, lc = lane & 7;

  for (int kt = 0; kt < 64; ++kt) {
    const int k0 = kt * 64;
    __syncthreads();
#pragma unroll
    for (int i = 0; i < 4; i++) {
      int row = i * 32 + w * 8 + ls;
      const float* src = Abase + (size_t)row * 4096 + k0 + lc * 8;
      f32x4 v0 = *(const f32x4*)src;
      f32x4 v1 = *(const f32x4*)(src + 4);
      s16x8 hs;
#pragma unroll
      for (int e = 0; e < 4; e++) hs[e] = (short)f2bf(v0[e]);
#pragma unroll
      for (int e = 0; e < 4; e++) hs[4 + e] = (short)f2bf(v1[e]);
      int chunk = lc ^ (row & 7);
      *(s16x8*)(Ah + row * 64 + chunk * 8) = hs;
      if (is_sup) {
        s16x8 lsv;
#pragma unroll
        for (int e = 0; e < 4; e++)
          lsv[e] = (short)f2bf(v0[e] - bf2f((unsigned short)hs[e]));
#pragma unroll
        for (int e = 0; e < 4; e++)
          lsv[4 + e] = (short)f2bf(v1[e] - bf2f((unsigned short)hs[4 + e]));
        *(s16x8*)(Al + row * 64 + chunk * 8) = lsv;
      }
    }
#pragma unroll
    for (int j = 0; j < 4; j++) {
      int rowl = w * 32 + j * 8 + ls;
      int cch = (lc ^ (ls & 7)) * 8;
      size_t goff = (size_t)(bn * 128 + rowl) * 4096 + k0 + cch;
      gload_lds16(WhiT + goff, Bh + (w * 32 + j * 8) * 64);
      if (is_sup) gload_lds16(WloT + goff, Bl + (w * 32 + j * 8) * 64);
    }
    __syncthreads();
#pragma unroll
    for (int ks = 0; ks < 2; ++ks) {
      const int cx = ((ks * 4 + kg) ^ (fr & 7)) * 8;
      bf16x8 ahf[4], bhf[4];
#pragma unroll
      for (int mi = 0; mi < 4; mi++) {
        int arow = wr * 64 + mi * 16 + fr;
        ahf[mi] = __builtin_bit_cast(bf16x8, *(const s16x8*)(Ah + arow * 64 + cx));
      }
#pragma unroll
      for (int ni = 0; ni < 4; ni++) {
        int brow = wc * 64 + ni * 16 + fr;
        bhf[ni] = __builtin_bit_cast(bf16x8, *(const s16x8*)(Bh + brow * 64 + cx));
      }
      if (is_sup) {
        bf16x8 alf[4], blf[4];
#pragma unroll
        for (int mi = 0; mi < 4; mi++) {
          int arow = wr * 64 + mi * 16 + fr;
          alf[mi] =
              __builtin_bit_cast(bf16x8, *(const s16x8*)(Al + arow * 64 + cx));
        }
#pragma unroll
        for (int ni = 0; ni < 4; ni++) {
          int brow = wc * 64 + ni * 16 + fr;
          blf[ni] =
              __builtin_bit_cast(bf16x8, *(const s16x8*)(Bl + brow * 64 + cx));
        }
#pragma unroll
        for (int mi = 0; mi < 4; mi++)
#pragma unroll
          for (int ni = 0; ni < 4; ni++) {
            acc[mi][ni] = mfma16(ahf[mi], bhf[ni], acc[mi][ni]);
            acc[mi][ni] = mfma16(ahf[mi], blf[ni], acc[mi][ni]);
            acc[mi][ni] = mfma16(alf[mi], bhf[ni], acc[mi][ni]);
          }
      } else {
#pragma unroll
        for (int mi = 0; mi < 4; mi++)
#pragma unroll
          for (int ni = 0; ni < 4; ni++)
            acc[mi][ni] = mfma16(ahf[mi], bhf[ni], acc[mi][ni]);
      }
    }
  }
#pragma unroll
  for (int ni = 0; ni < 4; ni++) {
    int gc = bn * 128 + wc * 64 + ni * 16 + fr;
    float bv = bias[gc];
#pragma unroll
    for (int mi = 0; mi < 4; mi++) {
      int gr = bm * 128 + wr * 64 + mi * 16 + kg * 4;
#pragma unroll
      for (int r = 0; r < 4; r++)
        emb[(size_t)(gr + r) * 1024 + gc] = acc[mi][ni][r] + bv;
    }
  }
}

// ---- 3'. fallback monolithic gram+diag ------------------------------------
__global__ __launch_bounds__(256) void gramdiag2_k(const float* __restrict__ emb,
                                                   float* __restrict__ G) {
  if (blockIdx.x < 256) {
    int c = blockIdx.x >> 4, tl = blockIdx.x & 15, ti = tl >> 2, tj = tl & 3;
    __shared__ float AsT[32][68];
    __shared__ float BsT[32][68];
    int t = threadIdx.x, ty = t >> 4, tx = t & 15;
    const float* base = emb + (size_t)c * 256 * 1024;
    float acc[4][4] = {};
    for (int k0 = 0; k0 < 1024; k0 += 32) {
      __syncthreads();
      {
        int r = t >> 2, seg = t & 3;
        const float* pa = base + (size_t)(ti * 64 + r) * 1024 + k0 + seg * 8;
        f32x4 va0 = *(const f32x4*)pa, va1 = *(const f32x4*)(pa + 4);
#pragma unroll
        for (int e = 0; e < 4; e++) AsT[seg * 8 + e][r] = va0[e];
#pragma unroll
        for (int e = 0; e < 4; e++) AsT[seg * 8 + 4 + e][r] = va1[e];
        const float* pb = base + (size_t)(tj * 64 + r) * 1024 + k0 + seg * 8;
        f32x4 vb0 = *(const f32x4*)pb, vb1 = *(const f32x4*)(pb + 4);
#pragma unroll
        for (int e = 0; e < 4; e++) BsT[seg * 8 + e][r] = vb0[e];
#pragma unroll
        for (int e = 0; e < 4; e++) BsT[seg * 8 + 4 + e][r] = vb1[e];
      }
      __syncthreads();
#pragma unroll 4
      for (int kk = 0; kk < 32; kk++) {
        f32x4 av = *(const f32x4*)(&AsT[kk][ty * 4]);
        f32x4 bv = *(const f32x4*)(&BsT[kk][tx * 4]);
#pragma unroll
        for (int jdx = 0; jdx < 4; jdx++) {
          acc[0][jdx] = fmaf(av[0], bv[jdx], acc[0][jdx]);
          acc[1][jdx] = fmaf(av[1], bv[jdx], acc[1][jdx]);
          acc[2][jdx] = fmaf(av[2], bv[jdx], acc[2][jdx]);
          acc[3][jdx] = fmaf(av[3], bv[jdx], acc[3][jdx]);
        }
      }
    }
#pragma unroll
    for (int i = 0; i < 4; i++) {
      int gr = ti * 64 + ty * 4 + i;
#pragma unroll
      for (int j = 0; j < 4; j++) {
        int gcl = tj * 64 + tx * 4 + j;
        if (gr != gcl)
          G[(size_t)c * 65536 + (size_t)gr * 256 + gcl] = acc[i][j];
      }
    }
  } else {
    int r = (blockIdx.x - 256) * 4 + (threadIdx.x >> 6);
    int lane = threadIdx.x & 63;
    const float* x = emb + (size_t)r * 1024;
    double acc = 0.0;
#pragma unroll
    for (int ch = 0; ch < 16; ch++) {
      float v = x[ch * 64 + lane];
      acc = fma((double)v, (double)v, acc);
    }
#pragma unroll
    for (int st = 1; st < 64; st <<= 1) acc += __shfl_xor(acc, st);
    if (lane == 0) {
      int c = r >> 8, i = r & 255;
      G[(size_t)c * 65536 + (size_t)i * 256 + i] = (float)acc;
    }
  }
}

// ---- 5. one-wave-per-class kmeans: 64 threads, 4 points/lane, 0 barriers --
#define APPLY1(db, nb, gg, p)                        \
  if ((db) & 1u)  s[p][0] += ((nb) & 1u)  ? (gg) : -(gg); \
  if ((db) & 2u)  s[p][1] += ((nb) & 2u)  ? (gg) : -(gg); \
  if ((db) & 4u)  s[p][2] += ((nb) & 4u)  ? (gg) : -(gg); \
  if ((db) & 8u)  s[p][3] += ((nb) & 8u)  ? (gg) : -(gg); \
  if ((db) & 16u) s[p][4] += ((nb) & 16u) ? (gg) : -(gg);

__global__ __launch_bounds__(64) void kmeans3_k(const float* __restrict__ G,
                                                float* __restrict__ wts) {
  const int c = blockIdx.x;
  const int lane = threadIdx.x;  // one wave per class
  unsigned o0, o1, s0k, s1k;
  tf2x32(0u, 42u, 0u, (unsigned)c, o0, o1);
  tf2x32(o0, o1, 0u, 1u, s0k, s1k);
  unsigned long long key[4];
#pragma unroll
  for (int q = 0; q < 4; q++) {
    unsigned y0, y1;
    tf2x32(s0k, s1k, 0u, (unsigned)(lane + 64 * q), y0, y1);
    key[q] = ((unsigned long long)(y0 ^ y1) << 32) | (unsigned)(lane + 64 * q);
  }
  int idx5[5];
#pragma unroll
  for (int r = 0; r < 5; r++) {
    unsigned long long mn = key[0];
#pragma unroll
    for (int q = 1; q < 4; q++) mn = key[q] < mn ? key[q] : mn;
#pragma unroll
    for (int st = 1; st < 64; st <<= 1) {
      unsigned long long o = __shfl_xor(mn, st);
      mn = o < mn ? o : mn;
    }
    int widx = (int)(unsigned)(mn & 0xffffffffu);
    idx5[r] = widx;
#pragma unroll
    for (int q = 0; q < 4; q++)
      if (widx == lane + 64 * q) key[q] = ~0ull;
  }
  unsigned m[4];
#pragma unroll
  for (int q = 0; q < 4; q++) {
    unsigned mm = 0;
#pragma unroll
    for (int k = 0; k < 5; k++)
      if (idx5[k] == lane + 64 * q) mm |= 1u << k;
    m[q] = mm;
  }
  const float* Gc = G + (size_t)c * 65536;
  float s[4][5];
#pragma unroll
  for (int k = 0; k < 5; k++) {
    const float* row = Gc + (size_t)idx5[k] * 256;
#pragma unroll
    for (int q = 0; q < 4; q++) s[q][k] = row[lane + 64 * q];
  }
  float Minv[5] = {1.0f, 1.0f, 1.0f, 1.0f, 1.0f};

  for (int it = 0; it < 100; ++it) {
    float Tu[5], C2[5];
#pragma unroll
    for (int k = 0; k < 5; k++) {
      float v = 0.0f;
#pragma unroll
      for (int q = 0; q < 4; q++)
        v += ((m[q] >> k) & 1u) ? s[q][k] : 0.0f;
#pragma unroll
      for (int st = 1; st < 64; st <<= 1) v += __shfl_xor(v, st);
      float iv = Minv[k];
      Tu[k] = v * iv * iv;
      C2[k] = -2.0f * iv;
    }
    int a[4];
#pragma unroll
    for (int q = 0; q < 4; q++) {
      float d0 = fmaf(C2[0], s[q][0], Tu[0]);
      float d1 = fmaf(C2[1], s[q][1], Tu[1]);
      float d2 = fmaf(C2[2], s[q][2], Tu[2]);
      float d3 = fmaf(C2[3], s[q][3], Tu[3]);
      float d4 = fmaf(C2[4], s[q][4], Tu[4]);
      int at = 0;
      float dmn = d0;
      if (d1 < dmn) { dmn = d1; at = 1; }
      if (d2 < dmn) { dmn = d2; at = 2; }
      if (d3 < dmn) { dmn = d3; at = 3; }
      if (d4 < dmn) { dmn = d4; at = 4; }
      a[q] = at;
    }
    int cnt[5];
#pragma unroll
    for (int k = 0; k < 5; k++) {
      int v = (a[0] == k) + (a[1] == k) + (a[2] == k) + (a[3] == k);
#pragma unroll
      for (int st = 1; st < 64; st <<= 1) v += __shfl_xor(v, st);
      cnt[k] = v;
    }
    unsigned nm[4], dm[4];
#pragma unroll
    for (int q = 0; q < 4; q++) {
      unsigned nv = 0;
#pragma unroll
      for (int k = 0; k < 5; k++) {
        int bit = (cnt[k] > 0) ? (a[q] == k ? 1 : 0) : (int)((m[q] >> k) & 1u);
        nv |= ((unsigned)bit) << k;
      }
      nm[q] = nv;
      dm[q] = nv ^ m[q];
    }
    unsigned long long bal[4];
#pragma unroll
    for (int q = 0; q < 4; q++) bal[q] = __ballot(dm[q] != 0);
    if ((bal[0] | bal[1] | bal[2] | bal[3]) == 0) break;  // fixed point
#pragma unroll
    for (int q = 0; q < 4; q++) m[q] = nm[q];
#pragma unroll
    for (int k = 0; k < 5; k++)
      if (cnt[k] > 0) Minv[k] = 1.0f / (float)cnt[k];
#pragma unroll
    for (int q = 0; q < 4; q++) {
      unsigned long long mask = bal[q];
      while (mask) {
#define GATHER(i)                                                      \
        int j##i = -1;                                                 \
        unsigned d##i = 0, e##i = 0;                                   \
        float g##i##0 = 0, g##i##1 = 0, g##i##2 = 0, g##i##3 = 0;      \
        if (mask) {                                                    \
          j##i = __builtin_ctzll(mask);                                \
          mask &= mask - 1;                                            \
          d##i = __shfl(dm[q], j##i);                                  \
          e##i = __shfl(nm[q], j##i);                                  \
          const float* row = Gc + (size_t)(q * 64 + j##i) * 256 + lane;\
          g##i##0 = row[0];  g##i##1 = row[64];                        \
          g##i##2 = row[128]; g##i##3 = row[192];                      \
        }
        GATHER(0) GATHER(1) GATHER(2) GATHER(3)
        GATHER(4) GATHER(5) GATHER(6) GATHER(7)
#undef GATHER
#define DOAPPLY(i)                        \
        if (j##i >= 0) {                  \
          APPLY1(d##i, e##i, g##i##0, 0)  \
          APPLY1(d##i, e##i, g##i##1, 1)  \
          APPLY1(d##i, e##i, g##i##2, 2)  \
          APPLY1(d##i, e##i, g##i##3, 3)  \
        }
        DOAPPLY(0) DOAPPLY(1) DOAPPLY(2) DOAPPLY(3)
        DOAPPLY(4) DOAPPLY(5) DOAPPLY(6) DOAPPLY(7)
#undef DOAPPLY
      }
    }
  }
#pragma unroll
  for (int q = 0; q < 4; q++) {
    float wv = 0.0f;
#pragma unroll
    for (int k = 0; k < 5; k++)
      if ((m[q] >> k) & 1u) wv += 0.2f * Minv[k];
    wts[c * 256 + lane + 64 * q] = wv;
  }
}

// ---- 6a. proto partials: 256 blocks (c, 16-row segment) -------------------
__global__ __launch_bounds__(256) void proto1_k(const float* __restrict__ emb,
                                                const float* __restrict__ wts,
                                                float* __restrict__ part) {
  int c = blockIdx.x & 15, seg = blockIdx.x >> 4, t = threadIdx.x;
  __shared__ float wl[16];
  if (t < 16) wl[t] = wts[c * 256 + seg * 16 + t];
  __syncthreads();
  f32x4 acc = {};
  const float* base = emb + (size_t)(c * 256 + seg * 16) * 1024 + t * 4;
#pragma unroll
  for (int j = 0; j < 16; j++) {
    f32x4 v = *(const f32x4*)(base + (size_t)j * 1024);
    float wj = wl[j];
#pragma unroll
    for (int e = 0; e < 4; e++) acc[e] = fmaf(wj, v[e], acc[e]);
  }
  *(f32x4*)(part + ((size_t)seg * 16 + c) * 1024 + t * 4) = acc;
}

// ---- 6b. proto2p: reduce (fixed order) + |p|^2 ----------------------------
__global__ __launch_bounds__(256) void proto2p_k(const float* __restrict__ part,
                                                 float* __restrict__ protos,
                                                 float* __restrict__ psqb) {
  __shared__ float Tp[4];
  int c = blockIdx.x, t = threadIdx.x, lane = t & 63, w = t >> 6;
  f32x4 acc = {};
#pragma unroll
  for (int seg = 0; seg < 16; seg++) {
    f32x4 v = *(const f32x4*)(part + ((size_t)seg * 16 + c) * 1024 + t * 4);
#pragma unroll
    for (int e = 0; e < 4; e++) acc[e] += v[e];
  }
  *(f32x4*)(protos + (size_t)c * 1024 + t * 4) = acc;
  float s = acc[0] * acc[0] + acc[1] * acc[1] + acc[2] * acc[2] +
            acc[3] * acc[3];
  s = wave_sum(s);
  if (lane == 0) Tp[w] = s;
  __syncthreads();
  if (t == 0) psqb[c] = Tp[0] + Tp[1] + Tp[2] + Tp[3];
}

// ---- 7. qry GEMM + 2-pass fused cdist epilogue (41 KB LDS -> 3 blk/CU) ----
// dpart layout: dpart[(slice*8192 + grow)*17 + p], slice = bn*4 + quarter
// (32 slices of 32 cols each); p<16: dot partial, p==16: |q|^2 partial.
__global__ __launch_bounds__(256) void gemm_qry_dist_k(
    const short* __restrict__ Qhi, const short* __restrict__ WhiT,
    const float* __restrict__ bias, const float* __restrict__ protos,
    float* __restrict__ dpart) {
  __shared__ __align__(16) char smem[41984];  // 41 KB -> 3 blk/CU
  short* Ah = (short*)smem;                   // staging: 16 KiB
  short* Bh = (short*)(smem + 16384);         // staging: 16 KiB
  float (*pl)[129] = (float(*)[129])smem;                 // 8256 B
  float (*q_tile)[129] = (float(*)[129])(smem + 8320);    // 64x129 = 33024 B
  const int t = threadIdx.x;
  const int bid = blockIdx.x;
  const int bm = bid & 63, bn = bid >> 6;  // siblings +64 -> same XCD
  const int lane = t & 63, w = t >> 6;
  const int wr = w >> 1, wc = w & 1;
  const int fr = lane & 15, kg = lane >> 4;
  const int ls = lane >> 3, lc = lane & 7;
  const short* Ag = Qhi + (size_t)bm * 128 * 4096;
  f32x4 acc[4][4] = {};

  for (int kt = 0; kt < 64; ++kt) {
    const int k0 = kt * 64;
    __syncthreads();
    const int cch = (lc ^ ls) * 8;
#pragma unroll
    for (int j = 0; j < 4; j++) {
      int rowl = w * 32 + j * 8 + ls;
      size_t aoff = (size_t)rowl * 4096 + k0 + cch;
      size_t boff = (size_t)(bn * 128 + rowl) * 4096 + k0 + cch;
      int ldst = (w * 32 + j * 8) * 64;
      gload_lds16(Ag + aoff, Ah + ldst);
      gload_lds16(WhiT + boff, Bh + ldst);
    }
    __syncthreads();
#pragma unroll
    for (int ks = 0; ks < 2; ++ks) {
      const int cx = ((ks * 4 + kg) ^ (fr & 7)) * 8;
      bf16x8 ahf[4], bhf[4];
#pragma unroll
      for (int mi = 0; mi < 4; mi++) {
        int arow = wr * 64 + mi * 16 + fr;
        ahf[mi] = __builtin_bit_cast(bf16x8, *(const s16x8*)(Ah + arow * 64 + cx));
      }
#pragma unroll
      for (int ni = 0; ni < 4; ni++) {
        int brow = wc * 64 + ni * 16 + fr;
        bhf[ni] = __builtin_bit_cast(bf16x8, *(const s16x8*)(Bh + brow * 64 + cx));
      }
#pragma unroll
      for (int mi = 0; mi < 4; mi++)
#pragma unroll
        for (int ni = 0; ni < 4; ni++)
          acc[mi][ni] = mfma16(ahf[mi], bhf[ni], acc[mi][ni]);
    }
  }
  // ---- fused cdist epilogue, two row-half passes ----
  __syncthreads();  // staging reads done; smem reused as pl + q_tile
  {                 // protos chunk once: pl[p][cl]
    int p = t >> 4, cl0 = (t & 15) * 8;
    const float* src = protos + (size_t)p * 1024 + bn * 128 + cl0;
    f32x4 v0 = *(const f32x4*)src, v1 = *(const f32x4*)(src + 4);
#pragma unroll
    for (int e = 0; e < 4; e++) pl[p][cl0 + e] = v0[e];
#pragma unroll
    for (int e = 0; e < 4; e++) pl[p][cl0 + 4 + e] = v1[e];
  }
  const int row = t & 63, quarter = t >> 6;
#pragma unroll
  for (int half = 0; half < 2; half++) {
    if (wr == half) {  // waves owning this row-half write their acc
#pragma unroll
      for (int ni = 0; ni < 4; ni++) {
        int cl = wc * 64 + ni * 16 + fr;
        float bv = bias[bn * 128 + cl];
#pragma unroll
        for (int mi = 0; mi < 4; mi++) {
          int rl = mi * 16 + kg * 4;  // 0..63 within the half
#pragma unroll
          for (int r = 0; r < 4; r++) q_tile[rl + r][cl] = acc[mi][ni][r] + bv;
        }
      }
    }
    __syncthreads();
    float dot[16] = {};
    float qs = 0.0f;
#pragma unroll 4
    for (int ci = 0; ci < 32; ci++) {
      int c = quarter * 32 + ci;
      float v = q_tile[row][c];
      qs = fmaf(v, v, qs);
#pragma unroll
      for (int p = 0; p < 16; p++) dot[p] = fmaf(v, pl[p][c], dot[p]);
    }
    int grow = bm * 128 + half * 64 + row;
    float* dst = dpart + ((size_t)(bn * 4 + quarter) * 8192 + grow) * 17;
#pragma unroll
    for (int p = 0; p < 16; p++) dst[p] = dot[p];
    dst[16] = qs;
    __syncthreads();
  }
}

// ---- 8. distred: fixed-order slice sum -> -sqrt ---------------------------
__global__ __launch_bounds__(256) void distred_k(const float* __restrict__ dpart,
                                                 const float* __restrict__ psqb,
                                                 float* __restrict__ out) {
  int gid = blockIdx.x * 256 + threadIdx.x;  // 131072
  int row = gid >> 4, p = gid & 15;
  float dot = 0.0f, qs = 0.0f;
#pragma unroll
  for (int s = 0; s < 32; s++) {
    const float* src = dpart + ((size_t)s * 8192 + row) * 17;
    dot += src[p];
    qs += src[16];
  }
  float d2 = qs - 2.0f * dot + psqb[p];
  d2 = fmaxf(d2, 0.0f);
  out[(size_t)row * 16 + p] = -sqrtf(d2);
}

// ---- fallback proto + dist (emb-based) ------------------------------------
__global__ __launch_bounds__(256) void proto_k(const float* __restrict__ emb,
                                               const float* __restrict__ wts,
                                               float* __restrict__ protos) {
  int c = blockIdx.x, t = threadIdx.x;
  __shared__ float wl[256];
  wl[t] = wts[c * 256 + t];
  __syncthreads();
  f32x4 acc = {};
  const float* base = emb + (size_t)c * 256 * 1024 + t * 4;
  for (int j = 0; j < 256; j++) {
    f32x4 v = *(const f32x4*)(base + (size_t)j * 1024);
    float wj = wl[j];
#pragma unroll
    for (int e = 0; e < 4; e++) acc[e] = fmaf(wj, v[e], acc[e]);
  }
  *(f32x4*)(protos + (size_t)c * 1024 + t * 4) = acc;
}

__global__ __launch_bounds__(256) void dist_k(const float* __restrict__ emb,
                                              const float* __restrict__ protos,
                                              float* __restrict__ out) {
  __shared__ float P[16 * 1024];  // 64 KiB
  int t = threadIdx.x, lane = t & 63, w = t >> 6;
#pragma unroll
  for (int i = 0; i < 16; i++) {
    int off = i * 1024 + t * 4;
    *(f32x4*)(P + off) = *(const f32x4*)(protos + off);
  }
  __syncthreads();
  float psq_keep = 0.0f;
  for (int p = 0; p < 16; p++) {
    float partial = 0.0f;
#pragma unroll
    for (int ch = 0; ch < 16; ch++) {
      float x = P[p * 1024 + ch * 64 + lane];
      partial = fmaf(x, x, partial);
    }
    partial = wave_sum(partial);
    if (lane == p) psq_keep = partial;
  }
  const float* qbase = emb + (size_t)4096 * 1024;
  int r0 = blockIdx.x * 16 + w * 4;
  for (int ri = 0; ri < 4; ri++) {
    int row = r0 + ri;
    const float* q = qbase + (size_t)row * 1024;
    float qv[16];
#pragma unroll
    for (int ch = 0; ch < 16; ch++) qv[ch] = q[ch * 64 + lane];
    float qsq = 0.0f;
#pragma unroll
    for (int ch = 0; ch < 16; ch++) qsq = fmaf(qv[ch], qv[ch], qsq);
    qsq = wave_sum(qsq);
    float dsel = 0.0f;
    for (int p = 0; p < 16; p++) {
      float dp = 0.0f;
#pragma unroll
      for (int ch = 0; ch < 16; ch++)
        dp = fmaf(qv[ch], P[p * 1024 + ch * 64 + lane], dp);
      dp = wave_sum(dp);
      if (lane == p) dsel = dp;
    }
    if (lane < 16) {
      float d2 = qsq - 2.0f * dsel + psq_keep;
      d2 = fmaxf(d2, 0.0f);
      out[(size_t)row * 16 + lane] = -sqrtf(d2);
    }
  }
}

// ---------------- launch ---------------------------------------------------
extern "C" void kernel_launch(void* const* d_in, const int* in_sizes, int n_in,
                              void* d_out, int out_size, void* d_ws,
                              size_t ws_size, hipStream_t stream) {
  const float* sup = (const float*)d_in[0];
  const float* qry = (const float*)d_in[1];
  const float* W = (const float*)d_in[2];
  const float* b = (const float*)d_in[3];
  float* out = (float*)d_out;
  char* ws = (char*)d_ws;
  (void)in_sizes; (void)n_in; (void)out_size;

  const size_t NEED_FAST = 206651392ULL;  // ~197 MiB
  if (ws_size >= NEED_FAST) {
    short* WhiT = (short*)(ws + 0);            //  8 MiB
    short* WloT = (short*)(ws + 8388608);      //  8 MiB
    short* Shi = (short*)(ws + 16777216);      // 32 MiB (dead after supq)
    short* Slo = (short*)(ws + 50331648);      // 32 MiB (dead after supq)
    short* Qhi = (short*)(ws + 83886080);      // 64 MiB
    float* emb = (float*)(ws + 150994944);     // 48 MiB (sup rows only)
    float* G = (float*)(ws + 201326592);       //  4 MiB
    float* wts = (float*)(ws + 205520896);     // 16 KiB
    float* protos = (float*)(ws + 205537280);  // 64 KiB
    float* part1 = (float*)(ws + 205602816);   //  1 MiB (proto partials)
    float* dpart = (float*)(ws + 16777216);    // 17.8 MiB (over dead Shi)
    float* psqb = (float*)(ws + 50331648);     // 64 B (over dead Slo)
    float* Gp = (float*)(ws + 50335744);       // 16 MiB (over dead Slo +4K)

    prep_sw_k<<<2048, 256, 0, stream>>>(W, sup, WhiT, WloT, Shi, Slo);
    gemm_supq_k<<<768, 256, 0, stream>>>(Shi, Slo, WhiT, WloT, b, emb, qry,
                                         Qhi);
    gram_part_k<<<1024, 256, 0, stream>>>(emb, Gp);
    greduce_k<<<2048, 256, 0, stream>>>(Gp, emb, G);
    kmeans3_k<<<16, 64, 0, stream>>>(G, wts);
    proto1_k<<<256, 256, 0, stream>>>(emb, wts, part1);
    proto2p_k<<<16, 256, 0, stream>>>(part1, protos, psqb);
    gemm_qry_dist_k<<<512, 256, 0, stream>>>(Qhi, WhiT, b, protos, dpart);
    distred_k<<<512, 256, 0, stream>>>(dpart, psqb, out);
  } else {
    short* WhiT = (short*)(ws + 0);
    short* WloT = (short*)(ws + 8388608);
    float* emb = (float*)(ws + 16777216);
    float* G = (float*)(ws + 67108864);
    float* wts = (float*)(ws + 71303168);
    float* protos = (float*)(ws + 71319552);

    prep_sw_k<<<1024, 256, 0, stream>>>(W, sup, WhiT, WloT, (short*)0,
                                        (short*)0);
    gemm_all_k<<<768, 256, 0, stream>>>(sup, qry, WhiT, WloT, b, emb);
    gramdiag2_k<<<1280, 256, 0, stream>>>(emb, G);
    kmeans3_k<<<16, 64, 0, stream>>>(G, wts);
    proto_k<<<16, 256, 0, stream>>>(emb, wts, protos);
    dist_k<<<512, 256, 0, stream>>>(emb, protos, out);
  }
}

// Round 15
// 407.157 us; speedup vs baseline: 1.1164x; 1.1164x over previous
//
#include <hip/hip_runtime.h>
#include <cstdint>
#include <cstddef>

// ClusterProtoNetwork (revert to round-13 best @409us + s16x8 W stores):
//  1) prep_sw: W split-transpose || sup->bf16 hi/lo
//  2) gemm_supq: sup GEMM (512 blk) || qry->bf16 convert (256 blk)
//  3) gramdiag2: K-major conflict-free gram (256) || f64 diag (1024)
//  4) kmeans3 (1 wave/class) -> proto1 -> proto2p (protos + |p|^2)
//  5) gemm_qry_dist: qry GEMM with fused cdist-partial epilogue (no qry emb)
//  6) distred: fixed-order slice reduction -> -sqrt
// JAX threefry (partitionable) RNG on-device.

typedef __attribute__((ext_vector_type(4))) float f32x4;
typedef __attribute__((ext_vector_type(8))) short s16x8;
typedef __attribute__((ext_vector_type(4))) short s16x4;
typedef __attribute__((ext_vector_type(8))) __bf16 bf16x8;

__device__ __forceinline__ unsigned short f2bf(float f) {
  unsigned u = __float_as_uint(f);
  return (unsigned short)((u + 0x7FFFu + ((u >> 16) & 1u)) >> 16);  // RTNE
}
__device__ __forceinline__ float bf2f(unsigned short h) {
  return __uint_as_float(((unsigned)h) << 16);
}

typedef const __attribute__((address_space(1))) void GV;
typedef __attribute__((address_space(3))) void LV;
__device__ __forceinline__ void gload_lds16(const void* g, void* l) {
  __builtin_amdgcn_global_load_lds((GV*)g, (LV*)l, 16, 0, 0);
}
__device__ __forceinline__ f32x4 mfma16(bf16x8 a, bf16x8 b, f32x4 c) {
  return __builtin_amdgcn_mfma_f32_16x16x32_bf16(a, b, c, 0, 0, 0);
}
__device__ __forceinline__ float wave_sum(float v) {
#pragma unroll
  for (int st = 1; st < 64; st <<= 1) v += __shfl_xor(v, st);
  return v;
}

// ---------------- Threefry-2x32 (JAX-exact, 20 rounds) ----------------
__device__ __forceinline__ void tf2x32(unsigned k0, unsigned k1, unsigned x0,
                                       unsigned x1, unsigned& y0, unsigned& y1) {
  unsigned ks0 = k0, ks1 = k1, ks2 = k0 ^ k1 ^ 0x1BD11BDAu;
  x0 += ks0; x1 += ks1;
  const int rA[4] = {13, 15, 26, 6};
  const int rB[4] = {17, 29, 16, 24};
#define ROTL(v, d) (((v) << (d)) | ((v) >> (32 - (d))))
#define RG(R)                                     \
  _Pragma("unroll") for (int i = 0; i < 4; i++) { \
    x0 += x1; x1 = ROTL(x1, R[i]); x1 ^= x0;      \
  }
  RG(rA); x0 += ks1; x1 += ks2 + 1u;
  RG(rB); x0 += ks2; x1 += ks0 + 2u;
  RG(rA); x0 += ks0; x1 += ks1 + 3u;
  RG(rB); x0 += ks1; x1 += ks2 + 4u;
  RG(rA); x0 += ks2; x1 += ks0 + 5u;
#undef RG
#undef ROTL
  y0 = x0; y1 = x1;
}

// ---- 1. prep_sw: W -> WhiT/WloT (transposed split) || sup -> Shi/Slo ------
__global__ __launch_bounds__(256) void prep_sw_k(
    const float* __restrict__ W, const float* __restrict__ sup,
    short* __restrict__ WhiT, short* __restrict__ WloT,
    short* __restrict__ Shi, short* __restrict__ Slo) {
  __shared__ float tile[64][65];
  int t = threadIdx.x;
  if (blockIdx.x < 1024) {  // prepw: 64 k-tiles x 16 n-tiles of 64x64
    int bk = blockIdx.x & 63, bn = blockIdx.x >> 6;
#pragma unroll
    for (int i = 0; i < 4; i++) {
      int row = i * 16 + (t >> 4);
      int col = (t & 15) * 4;
      f32x4 v =
          *(const f32x4*)(W + (size_t)(bk * 64 + row) * 1024 + bn * 64 + col);
      tile[row][col + 0] = v[0]; tile[row][col + 1] = v[1];
      tile[row][col + 2] = v[2]; tile[row][col + 3] = v[3];
    }
    __syncthreads();
    // s16x8 (16B) stores: same values/addresses as before, half the stores
#pragma unroll
    for (int i = 0; i < 2; i++) {
      int nrow = i * 32 + (t >> 3);
      int kcol = (t & 7) * 8;
      s16x8 hv, lv;
#pragma unroll
      for (int e = 0; e < 8; e++) {
        float v = tile[kcol + e][nrow];
        unsigned short h = f2bf(v);
        hv[e] = (short)h;
        lv[e] = (short)f2bf(v - bf2f(h));
      }
      size_t off = (size_t)(bn * 64 + nrow) * 4096 + bk * 64 + kcol;
      *(s16x8*)(WhiT + off) = hv;
      *(s16x8*)(WloT + off) = lv;
    }
  } else {  // sup convert: grid-stride over 2M 8-elem chunks
    const size_t sup_n8 = (size_t)4096 * 4096 / 8;
    size_t stride = (size_t)(gridDim.x - 1024) * 256;
    for (size_t gid = (size_t)(blockIdx.x - 1024) * 256 + t; gid < sup_n8;
         gid += stride) {
      const float* src = sup + gid * 8;
      f32x4 v0 = *(const f32x4*)src, v1 = *(const f32x4*)(src + 4);
      s16x8 h, l;
#pragma unroll
      for (int e = 0; e < 4; e++) {
        unsigned short hh = f2bf(v0[e]);
        h[e] = (short)hh; l[e] = (short)f2bf(v0[e] - bf2f(hh));
      }
#pragma unroll
      for (int e = 0; e < 4; e++) {
        unsigned short hh = f2bf(v1[e]);
        h[4 + e] = (short)hh; l[4 + e] = (short)f2bf(v1[e] - bf2f(hh));
      }
      *(s16x8*)(Shi + gid * 8) = h;
      *(s16x8*)(Slo + gid * 8) = l;
    }
  }
}

// ---- 2. gemm_supq: sup GEMM (512 blk, BM=64, 3-product) || qry convert ----
__global__ __launch_bounds__(256) void gemm_supq_k(
    const short* __restrict__ Shi, const short* __restrict__ Slo,
    const short* __restrict__ WhiT, const short* __restrict__ WloT,
    const float* __restrict__ bias, float* __restrict__ emb,
    const float* __restrict__ qry, short* __restrict__ Qhi) {
  __shared__ short lds[24576];  // 48 KiB (3 blk/CU)
  const int t = threadIdx.x;
  if (blockIdx.x < 512) {
    short* Ah = lds;              // [64][64]
    short* Al = lds + 4096;       // [64][64]
    short* Bh = lds + 8192;       // [128][64]
    short* Bl = lds + 16384;      // [128][64]
    const int bid = blockIdx.x;
    const int bm = bid & 63, bn = bid >> 6;  // siblings +64 -> same XCD
    const int lane = t & 63, w = t >> 6;
    const int wr = w >> 1, wc = w & 1;  // wave tile 32 x 64
    const int fr = lane & 15, kg = lane >> 4;
    const int ls = lane >> 3, lc = lane & 7;
    const short* Ag = Shi + (size_t)bm * 64 * 4096;
    const short* Alg = Slo + (size_t)bm * 64 * 4096;
    f32x4 acc[2][4] = {};

    for (int kt = 0; kt < 64; ++kt) {
      const int k0 = kt * 64;
      __syncthreads();
      const int cch = (lc ^ ls) * 8;
#pragma unroll
      for (int j = 0; j < 2; j++) {
        int rowl = w * 16 + j * 8 + ls;
        size_t aoff = (size_t)rowl * 4096 + k0 + cch;
        int ldst = (w * 16 + j * 8) * 64;
        gload_lds16(Ag + aoff, Ah + ldst);
        gload_lds16(Alg + aoff, Al + ldst);
      }
#pragma unroll
      for (int j = 0; j < 4; j++) {
        int rowl = w * 32 + j * 8 + ls;
        size_t boff = (size_t)(bn * 128 + rowl) * 4096 + k0 + cch;
        int ldst = (w * 32 + j * 8) * 64;
        gload_lds16(WhiT + boff, Bh + ldst);
        gload_lds16(WloT + boff, Bl + ldst);
      }
      __syncthreads();
#pragma unroll
      for (int ks = 0; ks < 2; ++ks) {
        const int cx = ((ks * 4 + kg) ^ (fr & 7)) * 8;
        bf16x8 ahf[2], alf[2], bhf[4], blf[4];
#pragma unroll
        for (int mi = 0; mi < 2; mi++) {
          int arow = wr * 32 + mi * 16 + fr;
          ahf[mi] =
              __builtin_bit_cast(bf16x8, *(const s16x8*)(Ah + arow * 64 + cx));
          alf[mi] =
              __builtin_bit_cast(bf16x8, *(const s16x8*)(Al + arow * 64 + cx));
        }
#pragma unroll
        for (int ni = 0; ni < 4; ni++) {
          int brow = wc * 64 + ni * 16 + fr;
          bhf[ni] =
              __builtin_bit_cast(bf16x8, *(const s16x8*)(Bh + brow * 64 + cx));
          blf[ni] =
              __builtin_bit_cast(bf16x8, *(const s16x8*)(Bl + brow * 64 + cx));
        }
#pragma unroll
        for (int mi = 0; mi < 2; mi++)
#pragma unroll
          for (int ni = 0; ni < 4; ni++) {
            acc[mi][ni] = mfma16(ahf[mi], bhf[ni], acc[mi][ni]);
            acc[mi][ni] = mfma16(ahf[mi], blf[ni], acc[mi][ni]);
            acc[mi][ni] = mfma16(alf[mi], bhf[ni], acc[mi][ni]);
          }
      }
    }
#pragma unroll
    for (int ni = 0; ni < 4; ni++) {
      int gc = bn * 128 + wc * 64 + ni * 16 + fr;
      float bv = bias[gc];
#pragma unroll
      for (int mi = 0; mi < 2; mi++) {
        int gr = bm * 64 + wr * 32 + mi * 16 + kg * 4;
#pragma unroll
        for (int r = 0; r < 4; r++)
          emb[(size_t)(gr + r) * 1024 + gc] = acc[mi][ni][r] + bv;
      }
    }
  } else {
    // qry convert: grid-stride, hidden under sup GEMM (idle slot + spare BW)
    const size_t qry_n8 = (size_t)8192 * 4096 / 8;
    size_t stride = (size_t)(gridDim.x - 512) * 256;
    for (size_t gid = (size_t)(blockIdx.x - 512) * 256 + t; gid < qry_n8;
         gid += stride) {
      const float* src = qry + gid * 8;
      f32x4 v0 = *(const f32x4*)src, v1 = *(const f32x4*)(src + 4);
      s16x8 h;
#pragma unroll
      for (int e = 0; e < 4; e++) h[e] = (short)f2bf(v0[e]);
#pragma unroll
      for (int e = 0; e < 4; e++) h[4 + e] = (short)f2bf(v1[e]);
      *(s16x8*)(Qhi + gid * 8) = h;
    }
  }
}

// ---- 3. gramdiag2: K-major conflict-free gram (256) || f64 diag (1024) ----
__global__ __launch_bounds__(256) void gramdiag2_k(const float* __restrict__ emb,
                                                   float* __restrict__ G) {
  if (blockIdx.x < 256) {
    int c = blockIdx.x >> 4, tl = blockIdx.x & 15, ti = tl >> 2, tj = tl & 3;
    __shared__ float AsT[32][68];  // [kk][row]
    __shared__ float BsT[32][68];  // [kk][col]
    int t = threadIdx.x, ty = t >> 4, tx = t & 15;
    const float* base = emb + (size_t)c * 256 * 1024;
    float acc[4][4] = {};
    for (int k0 = 0; k0 < 1024; k0 += 32) {
      __syncthreads();
      {
        int r = t >> 2, seg = t & 3;
        const float* pa = base + (size_t)(ti * 64 + r) * 1024 + k0 + seg * 8;
        f32x4 va0 = *(const f32x4*)pa, va1 = *(const f32x4*)(pa + 4);
#pragma unroll
        for (int e = 0; e < 4; e++) AsT[seg * 8 + e][r] = va0[e];
#pragma unroll
        for (int e = 0; e < 4; e++) AsT[seg * 8 + 4 + e][r] = va1[e];
        const float* pb = base + (size_t)(tj * 64 + r) * 1024 + k0 + seg * 8;
        f32x4 vb0 = *(const f32x4*)pb, vb1 = *(const f32x4*)(pb + 4);
#pragma unroll
        for (int e = 0; e < 4; e++) BsT[seg * 8 + e][r] = vb0[e];
#pragma unroll
        for (int e = 0; e < 4; e++) BsT[seg * 8 + 4 + e][r] = vb1[e];
      }
      __syncthreads();
#pragma unroll 4
      for (int kk = 0; kk < 32; kk++) {
        f32x4 av = *(const f32x4*)(&AsT[kk][ty * 4]);
        f32x4 bv = *(const f32x4*)(&BsT[kk][tx * 4]);
#pragma unroll
        for (int jdx = 0; jdx < 4; jdx++) {
          acc[0][jdx] = fmaf(av[0], bv[jdx], acc[0][jdx]);
          acc[1][jdx] = fmaf(av[1], bv[jdx], acc[1][jdx]);
          acc[2][jdx] = fmaf(av[2], bv[jdx], acc[2][jdx]);
          acc[3][jdx] = fmaf(av[3], bv[jdx], acc[3][jdx]);
        }
      }
    }
#pragma unroll
    for (int i = 0; i < 4; i++) {
      int gr = ti * 64 + ty * 4 + i;
#pragma unroll
      for (int j = 0; j < 4; j++) {
        int gcl = tj * 64 + tx * 4 + j;
        if (gr != gcl)  // diagonal owned by the diag blocks
          G[(size_t)c * 65536 + (size_t)gr * 256 + gcl] = acc[i][j];
      }
    }
  } else {
    int r = (blockIdx.x - 256) * 4 + (threadIdx.x >> 6);  // support row
    int lane = threadIdx.x & 63;
    const float* x = emb + (size_t)r * 1024;
    double acc = 0.0;
#pragma unroll
    for (int ch = 0; ch < 16; ch++) {
      float v = x[ch * 64 + lane];
      acc = fma((double)v, (double)v, acc);
    }
#pragma unroll
    for (int st = 1; st < 64; st <<= 1) acc += __shfl_xor(acc, st);
    if (lane == 0) {
      int c = r >> 8, i = r & 255;
      G[(size_t)c * 65536 + (size_t)i * 256 + i] = (float)acc;
    }
  }
}

// ---- 2'. fallback GEMM (in-loop convert; used when ws too small) ----------
__global__ __launch_bounds__(256) void gemm_all_k(
    const float* __restrict__ sup, const float* __restrict__ qry,
    const short* __restrict__ WhiT, const short* __restrict__ WloT,
    const float* __restrict__ bias, float* __restrict__ emb) {
  __shared__ short lds[4 * 128 * 64];
  short* Ah = lds;
  short* Al = lds + 8192;
  short* Bh = lds + 16384;
  short* Bl = lds + 24576;
  const int bid = blockIdx.x;
  const int bm = bid % 96, bn = bid / 96;
  const bool is_sup = bm < 32;
  const int t = threadIdx.x, lane = t & 63, w = t >> 6;
  const int wr = w >> 1, wc = w & 1;
  const int fr = lane & 15, kg = lane >> 4;
  const float* Abase = is_sup ? (sup + (size_t)bm * 128 * 4096)
                              : (qry + (size_t)(bm - 32) * 128 * 4096);
  f32x4 acc[4][4] = {};
  const int ls = lane >> 3, lc = lane & 7;

  for (int kt = 0; kt < 64; ++kt) {
    const int k0 = kt * 64;
    __syncthreads();
#pragma unroll
    for (int i = 0; i < 4; i++) {
      int row = i * 32 + w * 8 + ls;
      const float* src = Abase + (size_t)row * 4096 + k0 + lc * 8;
      f32x4 v0 = *(const f32x4*)src;
      f32x4 v1 = *(const f32x4*)(src + 4);
      s16x8 hs;
#pragma unroll
      for (int e = 0; e < 4; e++) hs[e] = (short)f2bf(v0[e]);
#pragma unroll
      for (int e = 0; e < 4; e++) hs[4 + e] = (short)f2bf(v1[e]);
      int chunk = lc ^ (row & 7);
      *(s16x8*)(Ah + row * 64 + chunk * 8) = hs;
      if (is_sup) {
        s16x8 lsv;
#pragma unroll
        for (int e = 0; e < 4; e++)
          lsv[e] = (short)f2bf(v0[e] - bf2f((unsigned short)hs[e]));
#pragma unroll
        for (int e = 0; e < 4; e++)
          lsv[4 + e] = (short)f2bf(v1[e] - bf2f((unsigned short)hs[4 + e]));
        *(s16x8*)(Al + row * 64 + chunk * 8) = lsv;
      }
    }
#pragma unroll
    for (int j = 0; j < 4; j++) {
      int rowl = w * 32 + j * 8 + ls;
      int cch = (lc ^ (ls & 7)) * 8;
      size_t goff = (size_t)(bn * 128 + rowl) * 4096 + k0 + cch;
      gload_lds16(WhiT + goff, Bh + (w * 32 + j * 8) * 64);
      if (is_sup) gload_lds16(WloT + goff, Bl + (w * 32 + j * 8) * 64);
    }
    __syncthreads();
#pragma unroll
    for (int ks = 0; ks < 2; ++ks) {
      const int cx = ((ks * 4 + kg) ^ (fr & 7)) * 8;
      bf16x8 ahf[4], bhf[4];
#pragma unroll
      for (int mi = 0; mi < 4; mi++) {
        int arow = wr * 64 + mi * 16 + fr;
        ahf[mi] = __builtin_bit_cast(bf16x8, *(const s16x8*)(Ah + arow * 64 + cx));
      }
#pragma unroll
      for (int ni = 0; ni < 4; ni++) {
        int brow = wc * 64 + ni * 16 + fr;
        bhf[ni] = __builtin_bit_cast(bf16x8, *(const s16x8*)(Bh + brow * 64 + cx));
      }
      if (is_sup) {
        bf16x8 alf[4], blf[4];
#pragma unroll
        for (int mi = 0; mi < 4; mi++) {
          int arow = wr * 64 + mi * 16 + fr;
          alf[mi] =
              __builtin_bit_cast(bf16x8, *(const s16x8*)(Al + arow * 64 + cx));
        }
#pragma unroll
        for (int ni = 0; ni < 4; ni++) {
          int brow = wc * 64 + ni * 16 + fr;
          blf[ni] =
              __builtin_bit_cast(bf16x8, *(const s16x8*)(Bl + brow * 64 + cx));
        }
#pragma unroll
        for (int mi = 0; mi < 4; mi++)
#pragma unroll
          for (int ni = 0; ni < 4; ni++) {
            acc[mi][ni] = mfma16(ahf[mi], bhf[ni], acc[mi][ni]);
            acc[mi][ni] = mfma16(ahf[mi], blf[ni], acc[mi][ni]);
            acc[mi][ni] = mfma16(alf[mi], bhf[ni], acc[mi][ni]);
          }
      } else {
#pragma unroll
        for (int mi = 0; mi < 4; mi++)
#pragma unroll
          for (int ni = 0; ni < 4; ni++)
            acc[mi][ni] = mfma16(ahf[mi], bhf[ni], acc[mi][ni]);
      }
    }
  }
#pragma unroll
  for (int ni = 0; ni < 4; ni++) {
    int gc = bn * 128 + wc * 64 + ni * 16 + fr;
    float bv = bias[gc];
#pragma unroll
    for (int mi = 0; mi < 4; mi++) {
      int gr = bm * 128 + wr * 64 + mi * 16 + kg * 4;
#pragma unroll
      for (int r = 0; r < 4; r++)
        emb[(size_t)(gr + r) * 1024 + gc] = acc[mi][ni][r] + bv;
    }
  }
}

// ---- 5. one-wave-per-class kmeans: 64 threads, 4 points/lane, 0 barriers --
#define APPLY1(db, nb, gg, p)                        \
  if ((db) & 1u)  s[p][0] += ((nb) & 1u)  ? (gg) : -(gg); \
  if ((db) & 2u)  s[p][1] += ((nb) & 2u)  ? (gg) : -(gg); \
  if ((db) & 4u)  s[p][2] += ((nb) & 4u)  ? (gg) : -(gg); \
  if ((db) & 8u)  s[p][3] += ((nb) & 8u)  ? (gg) : -(gg); \
  if ((db) & 16u) s[p][4] += ((nb) & 16u) ? (gg) : -(gg);

__global__ __launch_bounds__(64) void kmeans3_k(const float* __restrict__ G,
                                                float* __restrict__ wts) {
  const int c = blockIdx.x;
  const int lane = threadIdx.x;  // one wave per class
  unsigned o0, o1, s0k, s1k;
  tf2x32(0u, 42u, 0u, (unsigned)c, o0, o1);
  tf2x32(o0, o1, 0u, 1u, s0k, s1k);
  unsigned long long key[4];
#pragma unroll
  for (int q = 0; q < 4; q++) {
    unsigned y0, y1;
    tf2x32(s0k, s1k, 0u, (unsigned)(lane + 64 * q), y0, y1);
    key[q] = ((unsigned long long)(y0 ^ y1) << 32) | (unsigned)(lane + 64 * q);
  }
  int idx5[5];
#pragma unroll
  for (int r = 0; r < 5; r++) {
    unsigned long long mn = key[0];
#pragma unroll
    for (int q = 1; q < 4; q++) mn = key[q] < mn ? key[q] : mn;
#pragma unroll
    for (int st = 1; st < 64; st <<= 1) {
      unsigned long long o = __shfl_xor(mn, st);
      mn = o < mn ? o : mn;
    }
    int widx = (int)(unsigned)(mn & 0xffffffffu);
    idx5[r] = widx;
#pragma unroll
    for (int q = 0; q < 4; q++)
      if (widx == lane + 64 * q) key[q] = ~0ull;
  }
  unsigned m[4];
#pragma unroll
  for (int q = 0; q < 4; q++) {
    unsigned mm = 0;
#pragma unroll
    for (int k = 0; k < 5; k++)
      if (idx5[k] == lane + 64 * q) mm |= 1u << k;
    m[q] = mm;
  }
  const float* Gc = G + (size_t)c * 65536;
  float s[4][5];
#pragma unroll
  for (int k = 0; k < 5; k++) {
    const float* row = Gc + (size_t)idx5[k] * 256;
#pragma unroll
    for (int q = 0; q < 4; q++) s[q][k] = row[lane + 64 * q];
  }
  float Minv[5] = {1.0f, 1.0f, 1.0f, 1.0f, 1.0f};

  for (int it = 0; it < 100; ++it) {
    float Tu[5], C2[5];
#pragma unroll
    for (int k = 0; k < 5; k++) {
      float v = 0.0f;
#pragma unroll
      for (int q = 0; q < 4; q++)
        v += ((m[q] >> k) & 1u) ? s[q][k] : 0.0f;
#pragma unroll
      for (int st = 1; st < 64; st <<= 1) v += __shfl_xor(v, st);
      float iv = Minv[k];
      Tu[k] = v * iv * iv;
      C2[k] = -2.0f * iv;
    }
    int a[4];
#pragma unroll
    for (int q = 0; q < 4; q++) {
      float d0 = fmaf(C2[0], s[q][0], Tu[0]);
      float d1 = fmaf(C2[1], s[q][1], Tu[1]);
      float d2 = fmaf(C2[2], s[q][2], Tu[2]);
      float d3 = fmaf(C2[3], s[q][3], Tu[3]);
      float d4 = fmaf(C2[4], s[q][4], Tu[4]);
      int at = 0;
      float dmn = d0;
      if (d1 < dmn) { dmn = d1; at = 1; }
      if (d2 < dmn) { dmn = d2; at = 2; }
      if (d3 < dmn) { dmn = d3; at = 3; }
      if (d4 < dmn) { dmn = d4; at = 4; }
      a[q] = at;
    }
    int cnt[5];
#pragma unroll
    for (int k = 0; k < 5; k++) {
      int v = (a[0] == k) + (a[1] == k) + (a[2] == k) + (a[3] == k);
#pragma unroll
      for (int st = 1; st < 64; st <<= 1) v += __shfl_xor(v, st);
      cnt[k] = v;
    }
    unsigned nm[4], dm[4];
#pragma unroll
    for (int q = 0; q < 4; q++) {
      unsigned nv = 0;
#pragma unroll
      for (int k = 0; k < 5; k++) {
        int bit = (cnt[k] > 0) ? (a[q] == k ? 1 : 0) : (int)((m[q] >> k) & 1u);
        nv |= ((unsigned)bit) << k;
      }
      nm[q] = nv;
      dm[q] = nv ^ m[q];
    }
    unsigned long long bal[4];
#pragma unroll
    for (int q = 0; q < 4; q++) bal[q] = __ballot(dm[q] != 0);
    if ((bal[0] | bal[1] | bal[2] | bal[3]) == 0) break;  // fixed point
#pragma unroll
    for (int q = 0; q < 4; q++) m[q] = nm[q];
#pragma unroll
    for (int k = 0; k < 5; k++)
      if (cnt[k] > 0) Minv[k] = 1.0f / (float)cnt[k];
#pragma unroll
    for (int q = 0; q < 4; q++) {
      unsigned long long mask = bal[q];
      while (mask) {
#define GATHER(i)                                                      \
        int j##i = -1;                                                 \
        unsigned d##i = 0, e##i = 0;                                   \
        float g##i##0 = 0, g##i##1 = 0, g##i##2 = 0, g##i##3 = 0;      \
        if (mask) {                                                    \
          j##i = __builtin_ctzll(mask);                                \
          mask &= mask - 1;                                            \
          d##i = __shfl(dm[q], j##i);                                  \
          e##i = __shfl(nm[q], j##i);                                  \
          const float* row = Gc + (size_t)(q * 64 + j##i) * 256 + lane;\
          g##i##0 = row[0];  g##i##1 = row[64];                        \
          g##i##2 = row[128]; g##i##3 = row[192];                      \
        }
        GATHER(0) GATHER(1) GATHER(2) GATHER(3)
        GATHER(4) GATHER(5) GATHER(6) GATHER(7)
#undef GATHER
#define DOAPPLY(i)                        \
        if (j##i >= 0) {                  \
          APPLY1(d##i, e##i, g##i##0, 0)  \
          APPLY1(d##i, e##i, g##i##1, 1)  \
          APPLY1(d##i, e##i, g##i##2, 2)  \
          APPLY1(d##i, e##i, g##i##3, 3)  \
        }
        DOAPPLY(0) DOAPPLY(1) DOAPPLY(2) DOAPPLY(3)
        DOAPPLY(4) DOAPPLY(5) DOAPPLY(6) DOAPPLY(7)
#undef DOAPPLY
      }
    }
  }
#pragma unroll
  for (int q = 0; q < 4; q++) {
    float wv = 0.0f;
#pragma unroll
    for (int k = 0; k < 5; k++)
      if ((m[q] >> k) & 1u) wv += 0.2f * Minv[k];
    wts[c * 256 + lane + 64 * q] = wv;
  }
}

// ---- 6a. proto partials: 256 blocks (c, 16-row segment) -------------------
__global__ __launch_bounds__(256) void proto1_k(const float* __restrict__ emb,
                                                const float* __restrict__ wts,
                                                float* __restrict__ part) {
  int c = blockIdx.x & 15, seg = blockIdx.x >> 4, t = threadIdx.x;
  __shared__ float wl[16];
  if (t < 16) wl[t] = wts[c * 256 + seg * 16 + t];
  __syncthreads();
  f32x4 acc = {};
  const float* base = emb + (size_t)(c * 256 + seg * 16) * 1024 + t * 4;
#pragma unroll
  for (int j = 0; j < 16; j++) {
    f32x4 v = *(const f32x4*)(base + (size_t)j * 1024);
    float wj = wl[j];
#pragma unroll
    for (int e = 0; e < 4; e++) acc[e] = fmaf(wj, v[e], acc[e]);
  }
  *(f32x4*)(part + ((size_t)seg * 16 + c) * 1024 + t * 4) = acc;
}

// ---- 6b. proto2p: reduce (fixed order) + |p|^2 ----------------------------
__global__ __launch_bounds__(256) void proto2p_k(const float* __restrict__ part,
                                                 float* __restrict__ protos,
                                                 float* __restrict__ psqb) {
  __shared__ float Tp[4];
  int c = blockIdx.x, t = threadIdx.x, lane = t & 63, w = t >> 6;
  f32x4 acc = {};
#pragma unroll
  for (int seg = 0; seg < 16; seg++) {
    f32x4 v = *(const f32x4*)(part + ((size_t)seg * 16 + c) * 1024 + t * 4);
#pragma unroll
    for (int e = 0; e < 4; e++) acc[e] += v[e];
  }
  *(f32x4*)(protos + (size_t)c * 1024 + t * 4) = acc;
  float s = acc[0] * acc[0] + acc[1] * acc[1] + acc[2] * acc[2] +
            acc[3] * acc[3];
  s = wave_sum(s);
  if (lane == 0) Tp[w] = s;
  __syncthreads();
  if (t == 0) psqb[c] = Tp[0] + Tp[1] + Tp[2] + Tp[3];
}

// ---- 7. qry GEMM with fused cdist-partial epilogue (no qry emb) -----------
// part layout: part[(slice*8192 + grow)*17 + p], slice = bn*2 + half (16),
// p in [0,16): dot partial over the slice's 64 cols; p==16: |q|^2 partial.
__global__ __launch_bounds__(256) void gemm_qry_dist_k(
    const short* __restrict__ Qhi, const short* __restrict__ WhiT,
    const float* __restrict__ bias, const float* __restrict__ protos,
    float* __restrict__ part) {
  __shared__ __align__(16) char smem[74496];
  short* Ah = (short*)smem;               // GEMM phase: 16 KiB
  short* Bh = (short*)(smem + 16384);     // GEMM phase: 16 KiB
  float (*q_tile)[129] = (float(*)[129])smem;          // 66048 B
  float (*pl)[132] = (float(*)[132])(smem + 66048);    // 16x132 = 8448 B
  const int t = threadIdx.x;
  const int bid = blockIdx.x;
  const int bm = bid & 63, bn = bid >> 6;  // siblings +64 -> same XCD
  const int lane = t & 63, w = t >> 6;
  const int wr = w >> 1, wc = w & 1;
  const int fr = lane & 15, kg = lane >> 4;
  const int ls = lane >> 3, lc = lane & 7;
  const short* Ag = Qhi + (size_t)bm * 128 * 4096;
  f32x4 acc[4][4] = {};

  for (int kt = 0; kt < 64; ++kt) {
    const int k0 = kt * 64;
    __syncthreads();
    const int cch = (lc ^ ls) * 8;
#pragma unroll
    for (int j = 0; j < 4; j++) {
      int rowl = w * 32 + j * 8 + ls;
      size_t aoff = (size_t)rowl * 4096 + k0 + cch;
      size_t boff = (size_t)(bn * 128 + rowl) * 4096 + k0 + cch;
      int ldst = (w * 32 + j * 8) * 64;
      gload_lds16(Ag + aoff, Ah + ldst);
      gload_lds16(WhiT + boff, Bh + ldst);
    }
    __syncthreads();
#pragma unroll
    for (int ks = 0; ks < 2; ++ks) {
      const int cx = ((ks * 4 + kg) ^ (fr & 7)) * 8;
      bf16x8 ahf[4], bhf[4];
#pragma unroll
      for (int mi = 0; mi < 4; mi++) {
        int arow = wr * 64 + mi * 16 + fr;
        ahf[mi] = __builtin_bit_cast(bf16x8, *(const s16x8*)(Ah + arow * 64 + cx));
      }
#pragma unroll
      for (int ni = 0; ni < 4; ni++) {
        int brow = wc * 64 + ni * 16 + fr;
        bhf[ni] = __builtin_bit_cast(bf16x8, *(const s16x8*)(Bh + brow * 64 + cx));
      }
#pragma unroll
      for (int mi = 0; mi < 4; mi++)
#pragma unroll
        for (int ni = 0; ni < 4; ni++)
          acc[mi][ni] = mfma16(ahf[mi], bhf[ni], acc[mi][ni]);
    }
  }
  // ---- fused cdist epilogue ----
  __syncthreads();  // staging LDS reads done; reuse as q_tile
#pragma unroll
  for (int ni = 0; ni < 4; ni++) {
    int cl = wc * 64 + ni * 16 + fr;
    float bv = bias[bn * 128 + cl];
#pragma unroll
    for (int mi = 0; mi < 4; mi++) {
      int rl = wr * 64 + mi * 16 + kg * 4;
#pragma unroll
      for (int r = 0; r < 4; r++) q_tile[rl + r][cl] = acc[mi][ni][r] + bv;
    }
  }
  {  // protos chunk: pl[p][cl], coalesced loads
    int p = t >> 4, cl0 = (t & 15) * 8;
    const float* src = protos + (size_t)p * 1024 + bn * 128 + cl0;
    f32x4 v0 = *(const f32x4*)src, v1 = *(const f32x4*)(src + 4);
#pragma unroll
    for (int e = 0; e < 4; e++) pl[p][cl0 + e] = v0[e];
#pragma unroll
    for (int e = 0; e < 4; e++) pl[p][cl0 + 4 + e] = v1[e];
  }
  __syncthreads();
  const int row = t & 127, half = t >> 7;
  float dot[16] = {};
  float qs = 0.0f;
#pragma unroll 4
  for (int ci = 0; ci < 64; ci++) {
    int c = half * 64 + ci;
    float v = q_tile[row][c];
    qs = fmaf(v, v, qs);
#pragma unroll
    for (int p = 0; p < 16; p++) dot[p] = fmaf(v, pl[p][c], dot[p]);
  }
  int grow = bm * 128 + row;
  float* dst = part + ((size_t)(bn * 2 + half) * 8192 + grow) * 17;
#pragma unroll
  for (int p = 0; p < 16; p++) dst[p] = dot[p];
  dst[16] = qs;
}

// ---- 8. distred: fixed-order slice sum -> -sqrt ---------------------------
__global__ __launch_bounds__(256) void distred_k(const float* __restrict__ part,
                                                 const float* __restrict__ psqb,
                                                 float* __restrict__ out) {
  int gid = blockIdx.x * 256 + threadIdx.x;  // 131072
  int row = gid >> 4, p = gid & 15;
  float dot = 0.0f, qs = 0.0f;
#pragma unroll
  for (int s = 0; s < 16; s++) {
    const float* src = part + ((size_t)s * 8192 + row) * 17;
    dot += src[p];
    qs += src[16];
  }
  float d2 = qs - 2.0f * dot + psqb[p];
  d2 = fmaxf(d2, 0.0f);
  out[(size_t)row * 16 + p] = -sqrtf(d2);
}

// ---- fallback proto + dist (emb-based) ------------------------------------
__global__ __launch_bounds__(256) void proto_k(const float* __restrict__ emb,
                                               const float* __restrict__ wts,
                                               float* __restrict__ protos) {
  int c = blockIdx.x, t = threadIdx.x;
  __shared__ float wl[256];
  wl[t] = wts[c * 256 + t];
  __syncthreads();
  f32x4 acc = {};
  const float* base = emb + (size_t)c * 256 * 1024 + t * 4;
  for (int j = 0; j < 256; j++) {
    f32x4 v = *(const f32x4*)(base + (size_t)j * 1024);
    float wj = wl[j];
#pragma unroll
    for (int e = 0; e < 4; e++) acc[e] = fmaf(wj, v[e], acc[e]);
  }
  *(f32x4*)(protos + (size_t)c * 1024 + t * 4) = acc;
}

__global__ __launch_bounds__(256) void dist_k(const float* __restrict__ emb,
                                              const float* __restrict__ protos,
                                              float* __restrict__ out) {
  __shared__ float P[16 * 1024];  // 64 KiB
  int t = threadIdx.x, lane = t & 63, w = t >> 6;
#pragma unroll
  for (int i = 0; i < 16; i++) {
    int off = i * 1024 + t * 4;
    *(f32x4*)(P + off) = *(const f32x4*)(protos + off);
  }
  __syncthreads();
  float psq_keep = 0.0f;
  for (int p = 0; p < 16; p++) {
    float partial = 0.0f;
#pragma unroll
    for (int ch = 0; ch < 16; ch++) {
      float x = P[p * 1024 + ch * 64 + lane];
      partial = fmaf(x, x, partial);
    }
    partial = wave_sum(partial);
    if (lane == p) psq_keep = partial;
  }
  const float* qbase = emb + (size_t)4096 * 1024;
  int r0 = blockIdx.x * 16 + w * 4;
  for (int ri = 0; ri < 4; ri++) {
    int row = r0 + ri;
    const float* q = qbase + (size_t)row * 1024;
    float qv[16];
#pragma unroll
    for (int ch = 0; ch < 16; ch++) qv[ch] = q[ch * 64 + lane];
    float qsq = 0.0f;
#pragma unroll
    for (int ch = 0; ch < 16; ch++) qsq = fmaf(qv[ch], qv[ch], qsq);
    qsq = wave_sum(qsq);
    float dsel = 0.0f;
    for (int p = 0; p < 16; p++) {
      float dp = 0.0f;
#pragma unroll
      for (int ch = 0; ch < 16; ch++)
        dp = fmaf(qv[ch], P[p * 1024 + ch * 64 + lane], dp);
      dp = wave_sum(dp);
      if (lane == p) dsel = dp;
    }
    if (lane < 16) {
      float d2 = qsq - 2.0f * dsel + psq_keep;
      d2 = fmaxf(d2, 0.0f);
      out[(size_t)row * 16 + lane] = -sqrtf(d2);
    }
  }
}

// ---------------- launch ---------------------------------------------------
extern "C" void kernel_launch(void* const* d_in, const int* in_sizes, int n_in,
                              void* d_out, int out_size, void* d_ws,
                              size_t ws_size, hipStream_t stream) {
  const float* sup = (const float*)d_in[0];
  const float* qry = (const float*)d_in[1];
  const float* W = (const float*)d_in[2];
  const float* b = (const float*)d_in[3];
  float* out = (float*)d_out;
  char* ws = (char*)d_ws;
  (void)in_sizes; (void)n_in; (void)out_size;

  const size_t NEED_FAST = 206651392ULL;  // ~197 MiB
  if (ws_size >= NEED_FAST) {
    short* WhiT = (short*)(ws + 0);            //  8 MiB
    short* WloT = (short*)(ws + 8388608);      //  8 MiB
    short* Shi = (short*)(ws + 16777216);      // 32 MiB (dead after supq)
    short* Slo = (short*)(ws + 50331648);      // 32 MiB (dead after supq)
    short* Qhi = (short*)(ws + 83886080);      // 64 MiB
    float* emb = (float*)(ws + 150994944);     // 48 MiB (sup rows only used)
    float* G = (float*)(ws + 201326592);       //  4 MiB
    float* wts = (float*)(ws + 205520896);     // 16 KiB
    float* protos = (float*)(ws + 205537280);  // 64 KiB
    float* part1 = (float*)(ws + 205602816);   //  1 MiB (proto partials)
    float* dpart = (float*)(ws + 16777216);    //  8.9 MiB (over dead Shi)
    float* psqb = (float*)(ws + 50331648);     //  64 B (over dead Slo)

    prep_sw_k<<<2048, 256, 0, stream>>>(W, sup, WhiT, WloT, Shi, Slo);
    gemm_supq_k<<<768, 256, 0, stream>>>(Shi, Slo, WhiT, WloT, b, emb, qry,
                                         Qhi);
    gramdiag2_k<<<1280, 256, 0, stream>>>(emb, G);
    kmeans3_k<<<16, 64, 0, stream>>>(G, wts);
    proto1_k<<<256, 256, 0, stream>>>(emb, wts, part1);
    proto2p_k<<<16, 256, 0, stream>>>(part1, protos, psqb);
    gemm_qry_dist_k<<<512, 256, 0, stream>>>(Qhi, WhiT, b, protos, dpart);
    distred_k<<<512, 256, 0, stream>>>(dpart, psqb, out);
  } else {
    short* WhiT = (short*)(ws + 0);
    short* WloT = (short*)(ws + 8388608);
    float* emb = (float*)(ws + 16777216);
    float* G = (float*)(ws + 67108864);
    float* wts = (float*)(ws + 71303168);
    float* protos = (float*)(ws + 71319552);

    prep_sw_k<<<1024, 256, 0, stream>>>(W, sup, WhiT, WloT, (short*)0,
                                        (short*)0);
    gemm_all_k<<<768, 256, 0, stream>>>(sup, qry, WhiT, WloT, b, emb);
    gramdiag2_k<<<1280, 256, 0, stream>>>(emb, G);
    kmeans3_k<<<16, 64, 0, stream>>>(G, wts);
    proto_k<<<16, 256, 0, stream>>>(emb, wts, protos);
    dist_k<<<512, 256, 0, stream>>>(emb, protos, out);
  }
}